// Round 2
// baseline (1164.191 us; speedup 1.0000x reference)
//
#include <hip/hip_runtime.h>
#include <math.h>

#define T 1024
#define H 1024
#define S 512
#define BB 2
#define HQ 16
#define HKV 4
#define DH 64
#define NI 4096
#define NE 8
#define EPSR 1.1920929e-07f

typedef unsigned short u16;
using short8 = __attribute__((ext_vector_type(8))) short;
using f32x4  = __attribute__((ext_vector_type(4))) float;
using float4v = __attribute__((ext_vector_type(4))) float;

__device__ __forceinline__ float bf2f(u16 u) {
    unsigned int x = ((unsigned int)u) << 16;
    return __uint_as_float(x);
}
__device__ __forceinline__ u16 f2bf(float f) {
    unsigned int x = __float_as_uint(f);
    return (u16)((x + 0x7fffu + ((x >> 16) & 1u)) >> 16);
}

// ---------------- RMSNorm: f32 in, bf16 out ----------------
__global__ __launch_bounds__(256) void rmsnorm_k(const float* __restrict__ xin,
                                                 const float* __restrict__ w,
                                                 u16* __restrict__ out) {
    int t = blockIdx.x;
    int tid = threadIdx.x;
    float vals[4];
    float ss = 0.f;
#pragma unroll
    for (int i = 0; i < 4; i++) {
        int c = tid + i * 256;
        float v = xin[(long)t * H + c];
        vals[i] = v;
        ss += v * v;
    }
    int lane = tid & 63, wid = tid >> 6;
#pragma unroll
    for (int o = 32; o; o >>= 1) ss += __shfl_xor(ss, o);
    __shared__ float red[4];
    __shared__ float rtot;
    if (lane == 0) red[wid] = ss;
    __syncthreads();
    if (tid == 0) {
        float s = red[0] + red[1] + red[2] + red[3];
        rtot = rsqrtf(s / (float)H + EPSR);
    }
    __syncthreads();
    float r = rtot;
#pragma unroll
    for (int i = 0; i < 4; i++) {
        int c = tid + i * 256;
        out[(long)t * H + c] = f2bf(vals[i] * r * w[c]);
    }
}

// ---------------- Generic 64x64 MFMA GEMM ----------------
// A: bf16 (u16*). B: f32, converted to bf16 in-register during staging.
// MODE 1: out_bf16 = A@B0 + bias0                       (QKV projections)
// MODE 2: out_f32  = A@B0 + bias0 + resid_f32           (O-proj + residual)
// MODE 3: act_bf16[compact] = silu(Ag@B0+b0)*(Ag@B1+b1) (A gathered by token list)
// MODE 4: atomicAdd(moe[token], scale*(A@B0 + b0))      (A = compact act rows)
template <int MODE>
__global__ __launch_bounds__(256) void gemm64(
    const u16* __restrict__ A, int lda,
    const float* __restrict__ B0, const float* __restrict__ B1, int ldb,
    const float* __restrict__ bias0, const float* __restrict__ bias1,
    const float* __restrict__ resid,
    void* __restrict__ out,
    int M, int N, int K,
    const int* __restrict__ ecnt, const int* __restrict__ eoff,
    const int* __restrict__ tlist, const float* __restrict__ tscale,
    u16* __restrict__ act, float* __restrict__ moe) {
    int e = blockIdx.z;
    int row0 = blockIdx.y * 64;
    int n0 = blockIdx.x * 64;
    int cnt = M, loff = 0;
    if (MODE >= 3) {
        cnt = ecnt[e];
        loff = eoff[e];
        if (row0 >= cnt) return;
        B0 += (long)e * (long)K * (long)ldb;
        bias0 += (long)e * N;
        if (MODE == 3) {
            B1 += (long)e * (long)K * (long)ldb;
            bias1 += (long)e * N;
        }
    }

    const int tid = threadIdx.x, lane = tid & 63, wv = tid >> 6;
    const int wm = wv >> 1, wc = wv & 1;

    __shared__ u16 As[64][40];
    __shared__ u16 Bs0[4][64][8];
    __shared__ u16 Bs1[(MODE == 3) ? 4 : 1][64][8];

    f32x4 acc0[2][2] = {};
    f32x4 acc1[2][2] = {};

    int arow = tid >> 2;
    int acol = (tid & 3) * 8;
    long arow_g;
    if (MODE == 3) {
        int r = row0 + arow;
        if (r >= cnt) r = cnt - 1;
        arow_g = tlist[loff + r];
    } else if (MODE == 4) {
        int r = row0 + arow;
        if (r >= cnt) r = cnt - 1;
        arow_g = loff + r;
    } else {
        arow_g = row0 + arow;
    }
    const u16* Aptr = A + arow_g * (long)lda + acol;

    int brow = tid >> 3;              // k index within 32-slice
    int bcol = (tid & 7) * 8;         // 8 consecutive n
    const float* B0ptr = B0 + (long)brow * ldb + n0 + bcol;
    const float* B1ptr = (MODE == 3) ? (B1 + (long)brow * ldb + n0 + bcol) : nullptr;

    for (int k0 = 0; k0 < K; k0 += 32) {
        short8 av = *(const short8*)(Aptr + k0);
        *(short8*)&As[arow][acol] = av;
        {
            float4v b0a = *(const float4v*)(B0ptr + (long)k0 * ldb);
            float4v b0b = *(const float4v*)(B0ptr + (long)k0 * ldb + 4);
#pragma unroll
            for (int u = 0; u < 4; u++) Bs0[brow >> 3][bcol + u][brow & 7] = f2bf(b0a[u]);
#pragma unroll
            for (int u = 0; u < 4; u++) Bs0[brow >> 3][bcol + 4 + u][brow & 7] = f2bf(b0b[u]);
        }
        if (MODE == 3) {
            float4v b1a = *(const float4v*)(B1ptr + (long)k0 * ldb);
            float4v b1b = *(const float4v*)(B1ptr + (long)k0 * ldb + 4);
#pragma unroll
            for (int u = 0; u < 4; u++) Bs1[brow >> 3][bcol + u][brow & 7] = f2bf(b1a[u]);
#pragma unroll
            for (int u = 0; u < 4; u++) Bs1[brow >> 3][bcol + 4 + u][brow & 7] = f2bf(b1b[u]);
        }
        __syncthreads();
        int quad = lane >> 4;
#pragma unroll
        for (int mi = 0; mi < 2; mi++) {
            int m = wm * 32 + mi * 16 + (lane & 15);
            short8 af = *(const short8*)&As[m][quad * 8];
#pragma unroll
            for (int ni = 0; ni < 2; ni++) {
                int n = wc * 32 + ni * 16 + (lane & 15);
                short8 bfr = *(const short8*)&Bs0[quad][n][0];
                acc0[mi][ni] = __builtin_amdgcn_mfma_f32_16x16x32_bf16(af, bfr, acc0[mi][ni], 0, 0, 0);
                if (MODE == 3) {
                    short8 bfu = *(const short8*)&Bs1[quad][n][0];
                    acc1[mi][ni] = __builtin_amdgcn_mfma_f32_16x16x32_bf16(af, bfu, acc1[mi][ni], 0, 0, 0);
                }
            }
        }
        __syncthreads();
    }

#pragma unroll
    for (int mi = 0; mi < 2; mi++) {
#pragma unroll
        for (int ni = 0; ni < 2; ni++) {
            int rbase = wm * 32 + mi * 16 + ((lane >> 4) << 2);
            int col = wc * 32 + ni * 16 + (lane & 15);
            int gcol = n0 + col;
#pragma unroll
            for (int r = 0; r < 4; r++) {
                int row = rbase + r;
                float v = acc0[mi][ni][r];
                if (MODE == 1) {
                    ((u16*)out)[(long)(row0 + row) * N + gcol] = f2bf(v + bias0[gcol]);
                } else if (MODE == 2) {
                    long idx = (long)(row0 + row) * N + gcol;
                    ((float*)out)[idx] = v + bias0[gcol] + resid[idx];
                } else if (MODE == 3) {
                    int rr = row0 + row;
                    if (rr < cnt) {
                        float g = v + bias0[gcol];
                        float u2 = acc1[mi][ni][r] + bias1[gcol];
                        float sg = g / (1.f + __expf(-g));
                        act[(long)(loff + rr) * NI + gcol] = f2bf(sg * u2);
                    }
                } else if (MODE == 4) {
                    int rr = row0 + row;
                    if (rr < cnt) {
                        int tok = tlist[loff + rr];
                        float sc = tscale[loff + rr];
                        atomicAdd(&moe[(long)tok * H + gcol], sc * (v + bias0[gcol]));
                    }
                }
            }
        }
    }
}

// ---------------- Attention: one wave per query row ----------------
__global__ __launch_bounds__(256) void attn_k(const u16* __restrict__ q,
                                              const u16* __restrict__ k,
                                              const u16* __restrict__ v,
                                              u16* __restrict__ o) {
    int tid = threadIdx.x, lane = tid & 63, wv = tid >> 6;
    int w = blockIdx.x * 4 + wv;
    int sq = w % S;
    int h = (w / S) % HQ;
    int b = w / (S * HQ);
    int hk = h >> 2;
    int tq = b * S + sq;
    __shared__ float qs[4][64];
    __shared__ float ps[4][512];
    float* Q = qs[wv];
    float* P = ps[wv];
    Q[lane] = bf2f(q[(long)tq * (HQ * DH) + h * DH + lane]) * 0.125f;
    __syncthreads();
    float sc[8];
    float m = -1e30f;
#pragma unroll
    for (int jj = 0; jj < 8; jj++) {
        int j = lane + jj * 64;
        const u16* kr = k + (long)(b * S + j) * (HKV * DH) + hk * DH;
        float a = 0.f;
#pragma unroll
        for (int c = 0; c < 8; c++) {
            short8 kv8 = *(const short8*)(kr + c * 8);
#pragma unroll
            for (int u = 0; u < 8; u++) a += Q[c * 8 + u] * bf2f((u16)kv8[u]);
        }
        sc[jj] = a;
        m = fmaxf(m, a);
    }
#pragma unroll
    for (int o2 = 32; o2; o2 >>= 1) m = fmaxf(m, __shfl_xor(m, o2));
    float l = 0.f;
#pragma unroll
    for (int jj = 0; jj < 8; jj++) {
        float p = __expf(sc[jj] - m);
        P[lane + jj * 64] = p;
        l += p;
    }
#pragma unroll
    for (int o2 = 32; o2; o2 >>= 1) l += __shfl_xor(l, o2);
    __syncthreads();
    float inv = 1.f / l;
    float acc = 0.f;
    const u16* vb = v + (long)(b * S) * (HKV * DH) + hk * DH + lane;
#pragma unroll 4
    for (int j = 0; j < 512; j++) acc += P[j] * bf2f(vb[(long)j * (HKV * DH)]);
    o[(long)tq * (HQ * DH) + h * DH + lane] = f2bf(acc * inv);
}

// ---------------- Router: one wave per token ----------------
__global__ __launch_bounds__(256) void router_k(const u16* __restrict__ t2,
                                                const float* __restrict__ rw,
                                                const float* __restrict__ rb,
                                                int* __restrict__ topi,
                                                float* __restrict__ probs) {
    int tid = threadIdx.x, lane = tid & 63, wv = tid >> 6;
    int tok = blockIdx.x * 4 + wv;
    float acc[NE] = {0.f, 0.f, 0.f, 0.f, 0.f, 0.f, 0.f, 0.f};
    for (int i = lane; i < H; i += 64) {
        float tv = bf2f(t2[(long)tok * H + i]);
        const float* r = rw + (long)i * NE;
        float4v ra = *(const float4v*)r;
        float4v rbv = *(const float4v*)(r + 4);
#pragma unroll
        for (int e = 0; e < 4; e++) acc[e] += tv * ra[e];
#pragma unroll
        for (int e = 0; e < 4; e++) acc[4 + e] += tv * rbv[e];
    }
#pragma unroll
    for (int e = 0; e < NE; e++)
#pragma unroll
        for (int o = 32; o; o >>= 1) acc[e] += __shfl_xor(acc[e], o);
    if (lane == 0) {
        float lg[NE];
#pragma unroll
        for (int e = 0; e < NE; e++) lg[e] = acc[e] + rb[e];
        int i0 = 0;
        float v0 = lg[0];
#pragma unroll
        for (int e = 1; e < NE; e++)
            if (lg[e] > v0) { v0 = lg[e]; i0 = e; }
        int i1 = -1;
        float v1 = -1e30f;
#pragma unroll
        for (int e = 0; e < NE; e++) {
            if (e == i0) continue;
            if (lg[e] > v1) { v1 = lg[e]; i1 = e; }
        }
        float ex = __expf(v1 - v0);
        float p0 = 1.f / (1.f + ex);
        topi[tok * 2] = i0;
        topi[tok * 2 + 1] = i1;
        probs[tok * 2] = p0;
        probs[tok * 2 + 1] = ex * p0;
    }
}

// ---------------- Build expert lists (single block) ----------------
__global__ void build_k(const int* __restrict__ topi, const float* __restrict__ probs,
                        int* __restrict__ gcnt, int* __restrict__ goff,
                        int* __restrict__ list, float* __restrict__ lscale) {
    __shared__ int cnt[NE], off[NE], fill[NE];
    int t = threadIdx.x;
    if (t < NE) cnt[t] = 0;
    __syncthreads();
    int e0 = topi[2 * t], e1 = topi[2 * t + 1];
    atomicAdd(&cnt[e0], 1);
    atomicAdd(&cnt[e1], 1);
    __syncthreads();
    if (t == 0) {
        int run = 0;
        for (int e = 0; e < NE; e++) {
            off[e] = run;
            fill[e] = run;
            run += cnt[e];
        }
    }
    __syncthreads();
    if (t < NE) {
        gcnt[t] = cnt[t];
        goff[t] = off[t];
    }
    int p0 = atomicAdd(&fill[e0], 1);
    list[p0] = t;
    lscale[p0] = probs[2 * t];
    int p1 = atomicAdd(&fill[e1], 1);
    list[p1] = t;
    lscale[p1] = probs[2 * t + 1];
}

__global__ void zero_k(float* __restrict__ p, int n) {
    int i = blockIdx.x * 256 + threadIdx.x;
    if (i < n) p[i] = 0.f;
}

__global__ void final_k(const float* __restrict__ x1, const float* __restrict__ moe,
                        float* __restrict__ out) {
    int i = blockIdx.x * 256 + threadIdx.x;
    out[i] = x1[i] + moe[i];
}

extern "C" void kernel_launch(void* const* d_in, const int* in_sizes, int n_in,
                              void* d_out, int out_size, void* d_ws, size_t ws_size,
                              hipStream_t stream) {
    const float* x = (const float*)d_in[0];
    const float* norm1_w = (const float*)d_in[1];
    const float* q_w = (const float*)d_in[2];
    const float* q_b = (const float*)d_in[3];
    const float* k_w = (const float*)d_in[4];
    const float* k_b = (const float*)d_in[5];
    const float* v_w = (const float*)d_in[6];
    const float* v_b = (const float*)d_in[7];
    const float* o_w = (const float*)d_in[8];
    const float* o_b = (const float*)d_in[9];
    const float* norm2_w = (const float*)d_in[10];
    const float* router_w = (const float*)d_in[11];
    const float* router_b = (const float*)d_in[12];
    const float* gate_w = (const float*)d_in[13];
    const float* gate_b = (const float*)d_in[14];
    const float* up_w = (const float*)d_in[15];
    const float* up_b = (const float*)d_in[16];
    const float* down_w = (const float*)d_in[17];
    const float* down_b = (const float*)d_in[18];

    char* w = (char*)d_ws;
    u16* h1 = (u16*)w;            w += (long)T * H * 2;
    u16* qb = (u16*)w;            w += (long)T * (HQ * DH) * 2;
    u16* kb = (u16*)w;            w += (long)T * (HKV * DH) * 2;
    u16* vb = (u16*)w;            w += (long)T * (HKV * DH) * 2;
    u16* ao = (u16*)w;            w += (long)T * (HQ * DH) * 2;
    float* x1 = (float*)w;        w += (long)T * H * 4;
    u16* t2 = (u16*)w;            w += (long)T * H * 2;
    int* topi = (int*)w;          w += T * 2 * 4;
    float* probs = (float*)w;     w += T * 2 * 4;
    int* gcnt = (int*)w;          w += 64;
    int* goff = (int*)w;          w += 64;
    int* list = (int*)w;          w += 2048 * 4;
    float* lscale = (float*)w;    w += 2048 * 4;
    u16* act = (u16*)w;           w += (long)2112 * NI * 2;
    float* moe = (float*)w;       w += (long)T * H * 4;

    // 1. rmsnorm1 (f32 x -> bf16 h1)
    rmsnorm_k<<<T, 256, 0, stream>>>(x, norm1_w, h1);
    // 2-4. QKV projections
    gemm64<1><<<dim3(16, 16, 1), 256, 0, stream>>>(h1, 1024, q_w, nullptr, 1024, q_b, nullptr,
                                                   nullptr, qb, 1024, 1024, 1024,
                                                   nullptr, nullptr, nullptr, nullptr, nullptr, nullptr);
    gemm64<1><<<dim3(4, 16, 1), 256, 0, stream>>>(h1, 1024, k_w, nullptr, 256, k_b, nullptr,
                                                  nullptr, kb, 1024, 256, 1024,
                                                  nullptr, nullptr, nullptr, nullptr, nullptr, nullptr);
    gemm64<1><<<dim3(4, 16, 1), 256, 0, stream>>>(h1, 1024, v_w, nullptr, 256, v_b, nullptr,
                                                  nullptr, vb, 1024, 256, 1024,
                                                  nullptr, nullptr, nullptr, nullptr, nullptr, nullptr);
    // 5. attention
    attn_k<<<(BB * HQ * S) / 4, 256, 0, stream>>>(qb, kb, vb, ao);
    // 6. O-proj + residual (f32 out)
    gemm64<2><<<dim3(16, 16, 1), 256, 0, stream>>>(ao, 1024, o_w, nullptr, 1024, o_b, nullptr,
                                                   x, x1, 1024, 1024, 1024,
                                                   nullptr, nullptr, nullptr, nullptr, nullptr, nullptr);
    // 7. rmsnorm2 (f32 x1 -> bf16 t2)
    rmsnorm_k<<<T, 256, 0, stream>>>(x1, norm2_w, t2);
    // 8. router
    router_k<<<T / 4, 256, 0, stream>>>(t2, router_w, router_b, topi, probs);
    // 9. build lists
    build_k<<<1, 1024, 0, stream>>>(topi, probs, gcnt, goff, list, lscale);
    // 10. zero moe
    zero_k<<<(T * H) / 256, 256, 0, stream>>>(moe, T * H);
    // 11. gate/up fused
    gemm64<3><<<dim3(NI / 64, 16, NE), 256, 0, stream>>>(t2, 1024, gate_w, up_w, NI,
                                                         gate_b, up_b, nullptr, nullptr,
                                                         0, NI, 1024,
                                                         gcnt, goff, list, lscale, act, nullptr);
    // 12. down + scatter
    gemm64<4><<<dim3(H / 64, 16, NE), 256, 0, stream>>>(act, NI, down_w, nullptr, H,
                                                        down_b, nullptr, nullptr, nullptr,
                                                        0, H, NI,
                                                        gcnt, goff, list, lscale, nullptr, moe);
    // 13. final add (f32 out)
    final_k<<<(T * H) / 256, 256, 0, stream>>>(x1, moe, (float*)d_out);
}

// Round 3
// 1063.728 us; speedup vs baseline: 1.0944x; 1.0944x over previous
//
#include <hip/hip_runtime.h>
#include <math.h>

#define T 1024
#define H 1024
#define S 512
#define BB 2
#define HQ 16
#define HKV 4
#define DH 64
#define NI 4096
#define NE 8
#define EPSR 1.1920929e-07f

typedef unsigned short u16;
using short8 = __attribute__((ext_vector_type(8))) short;
using f32x4  = __attribute__((ext_vector_type(4))) float;
using float4v = __attribute__((ext_vector_type(4))) float;

__device__ __forceinline__ float bf2f(u16 u) {
    unsigned int x = ((unsigned int)u) << 16;
    return __uint_as_float(x);
}
__device__ __forceinline__ u16 f2bf(float f) {
    unsigned int x = __float_as_uint(f);
    return (u16)((x + 0x7fffu + ((x >> 16) & 1u)) >> 16);
}

// ---------- Transpose + f32->bf16 convert: W[K][N] -> WT[N][K] ----------
__global__ __launch_bounds__(256) void transpose_k(const float* __restrict__ W,
                                                   u16* __restrict__ WT,
                                                   int K, int N,
                                                   long in_bs, long out_bs) {
    int z = blockIdx.z;
    W += z * in_bs;
    WT += z * out_bs;
    int n0 = blockIdx.x * 64, k0 = blockIdx.y * 64;
    __shared__ u16 tile[64][68];
    int t = threadIdx.x;
    int r = t >> 4, c = (t & 15) * 4;
#pragma unroll
    for (int p = 0; p < 4; p++) {
        float4v v = *(const float4v*)(W + (long)(k0 + r + p * 16) * N + n0 + c);
#pragma unroll
        for (int u = 0; u < 4; u++) tile[r + p * 16][c + u] = f2bf(v[u]);
    }
    __syncthreads();
    int n = t >> 3, k8 = (t & 7) * 8;
#pragma unroll
    for (int p = 0; p < 2; p++) {
        short8 o;
#pragma unroll
        for (int j = 0; j < 8; j++) o[j] = (short)tile[k8 + j][n + p * 32];
        *(short8*)(WT + (long)(n0 + n + p * 32) * K + k0 + k8) = o;
    }
}

// ---------------- RMSNorm: f32 in, bf16 out ----------------
__global__ __launch_bounds__(256) void rmsnorm_k(const float* __restrict__ xin,
                                                 const float* __restrict__ w,
                                                 u16* __restrict__ out) {
    int t = blockIdx.x;
    int tid = threadIdx.x;
    float vals[4];
    float ss = 0.f;
#pragma unroll
    for (int i = 0; i < 4; i++) {
        int c = tid + i * 256;
        float v = xin[(long)t * H + c];
        vals[i] = v;
        ss += v * v;
    }
    int lane = tid & 63, wid = tid >> 6;
#pragma unroll
    for (int o = 32; o; o >>= 1) ss += __shfl_xor(ss, o);
    __shared__ float red[4];
    __shared__ float rtot;
    if (lane == 0) red[wid] = ss;
    __syncthreads();
    if (tid == 0) {
        float s = red[0] + red[1] + red[2] + red[3];
        rtot = rsqrtf(s / (float)H + EPSR);
    }
    __syncthreads();
    float r = rtot;
#pragma unroll
    for (int i = 0; i < 4; i++) {
        int c = tid + i * 256;
        out[(long)t * H + c] = f2bf(vals[i] * r * w[c]);
    }
}

// ---------------- 128x128 MFMA GEMM, A bf16 [M][K], BT bf16 [N][K] ----------------
// MODE 1: out_bf16 = A@B + bias                       (fused QKV)
// MODE 2: out_f32  = A@B + bias + resid_f32           (O-proj + residual)
// MODE 3: act = silu(Ag@B0+b0)*(Ag@B1+b1)             (A gathered by token list)
// MODE 4: atomicAdd(moe[token], scale*(A@B0 + b0))    (A = compact act rows)
template <int MODE>
__global__ __launch_bounds__(256) void gemm128(
    const u16* __restrict__ A, int lda,
    const u16* __restrict__ BT0, const u16* __restrict__ BT1,
    const float* __restrict__ bias0, const float* __restrict__ bias1,
    const float* __restrict__ resid,
    void* __restrict__ out,
    int M, int N, int K,
    const int* __restrict__ ecnt, const int* __restrict__ eoff,
    const int* __restrict__ tlist, const float* __restrict__ tscale,
    u16* __restrict__ act, float* __restrict__ moe) {
    int e = blockIdx.z;
    int row0 = blockIdx.y * 128;
    int n0 = blockIdx.x * 128;
    int cnt = M, loff = 0;
    if (MODE >= 3) {
        cnt = ecnt[e];
        loff = eoff[e];
        if (row0 >= cnt) return;
        BT0 += (long)e * (long)K * (long)NI * ((MODE == 3) ? 1 : 0) + ((MODE == 4) ? (long)e * (long)K * (long)H : 0);
        bias0 += (long)e * N;
        if (MODE == 3) {
            BT1 += (long)e * (long)K * (long)NI;
            bias1 += (long)e * N;
        }
    }

    const int tid = threadIdx.x, lane = tid & 63, wv = tid >> 6;
    const int wm = wv >> 1, wn = wv & 1;
    const int quad = lane >> 4, lm = lane & 15;

    __shared__ u16 As[128][32];
    __shared__ u16 Bs0[128][32];
    __shared__ u16 Bs1[(MODE == 3) ? 128 : 1][32];

    f32x4 acc0[4][4] = {};
    f32x4 acc1[(MODE == 3) ? 4 : 1][4] = {};

    // staging indices: thread covers rows sa_row and sa_row+64, 8 k each
    int sa_row = tid >> 2;
    int sa_k = (tid & 3) * 8;
    long arow_g[2];
#pragma unroll
    for (int p = 0; p < 2; p++) {
        int r = row0 + sa_row + p * 64;
        if (MODE == 3) {
            if (r >= cnt) r = row0 + ((cnt - 1 - row0) > 0 ? (cnt - 1 - row0) : 0);
            int rr = (row0 + sa_row + p * 64 < cnt) ? (row0 + sa_row + p * 64) : (cnt - 1);
            arow_g[p] = tlist[loff + rr];
        } else if (MODE == 4) {
            int rr = (r < cnt) ? r : (cnt - 1);
            arow_g[p] = loff + rr;
        } else {
            arow_g[p] = r;
        }
    }
    const u16* Ap0 = A + arow_g[0] * (long)lda + sa_k;
    const u16* Ap1 = A + arow_g[1] * (long)lda + sa_k;
    const u16* Bp0 = BT0 + (long)(n0 + sa_row) * K + sa_k;
    const u16* Bp1 = BT0 + (long)(n0 + sa_row + 64) * K + sa_k;
    const u16* Cp0 = (MODE == 3) ? (BT1 + (long)(n0 + sa_row) * K + sa_k) : nullptr;
    const u16* Cp1 = (MODE == 3) ? (BT1 + (long)(n0 + sa_row + 64) * K + sa_k) : nullptr;

    for (int k0 = 0; k0 < K; k0 += 32) {
        short8 a0 = *(const short8*)(Ap0 + k0);
        short8 a1 = *(const short8*)(Ap1 + k0);
        short8 b0 = *(const short8*)(Bp0 + k0);
        short8 b1 = *(const short8*)(Bp1 + k0);
        short8 c0, c1;
        if (MODE == 3) {
            c0 = *(const short8*)(Cp0 + k0);
            c1 = *(const short8*)(Cp1 + k0);
        }
        __syncthreads();
        *(short8*)&As[sa_row][sa_k] = a0;
        *(short8*)&As[sa_row + 64][sa_k] = a1;
        *(short8*)&Bs0[sa_row][sa_k] = b0;
        *(short8*)&Bs0[sa_row + 64][sa_k] = b1;
        if (MODE == 3) {
            *(short8*)&Bs1[sa_row][sa_k] = c0;
            *(short8*)&Bs1[sa_row + 64][sa_k] = c1;
        }
        __syncthreads();
#pragma unroll
        for (int mi = 0; mi < 4; mi++) {
            short8 af = *(const short8*)&As[wm * 64 + mi * 16 + lm][quad * 8];
#pragma unroll
            for (int ni = 0; ni < 4; ni++) {
                short8 bf = *(const short8*)&Bs0[wn * 64 + ni * 16 + lm][quad * 8];
                acc0[mi][ni] = __builtin_amdgcn_mfma_f32_16x16x32_bf16(af, bf, acc0[mi][ni], 0, 0, 0);
                if (MODE == 3) {
                    short8 cf = *(const short8*)&Bs1[wn * 64 + ni * 16 + lm][quad * 8];
                    acc1[mi][ni] = __builtin_amdgcn_mfma_f32_16x16x32_bf16(af, cf, acc1[mi][ni], 0, 0, 0);
                }
            }
        }
    }

#pragma unroll
    for (int mi = 0; mi < 4; mi++) {
#pragma unroll
        for (int ni = 0; ni < 4; ni++) {
            int rbase = wm * 64 + mi * 16 + quad * 4;
            int gcol = n0 + wn * 64 + ni * 16 + lm;
#pragma unroll
            for (int r = 0; r < 4; r++) {
                int row = rbase + r;
                float v = acc0[mi][ni][r];
                if (MODE == 1) {
                    ((u16*)out)[(long)(row0 + row) * N + gcol] = f2bf(v + bias0[gcol]);
                } else if (MODE == 2) {
                    long idx = (long)(row0 + row) * N + gcol;
                    ((float*)out)[idx] = v + bias0[gcol] + resid[idx];
                } else if (MODE == 3) {
                    int rr = row0 + row;
                    if (rr < cnt) {
                        float g = v + bias0[gcol];
                        float u2 = acc1[mi][ni][r] + bias1[gcol];
                        float sg = g / (1.f + __expf(-g));
                        act[(long)(loff + rr) * NI + gcol] = f2bf(sg * u2);
                    }
                } else if (MODE == 4) {
                    int rr = row0 + row;
                    if (rr < cnt) {
                        int tok = tlist[loff + rr];
                        float sc = tscale[loff + rr];
                        atomicAdd(&moe[(long)tok * H + gcol], sc * (v + bias0[gcol]));
                    }
                }
            }
        }
    }
}

// ---------------- Attention: one wave per query row (qkv fused layout) ----------------
#define QKVLD 1536
__global__ __launch_bounds__(256) void attn_k(const u16* __restrict__ qkv,
                                              u16* __restrict__ o) {
    int tid = threadIdx.x, lane = tid & 63, wv = tid >> 6;
    int w = blockIdx.x * 4 + wv;
    int sq = w % S;
    int h = (w / S) % HQ;
    int b = w / (S * HQ);
    int hk = h >> 2;
    int tq = b * S + sq;
    __shared__ float qs[4][64];
    __shared__ float ps[4][512];
    float* Q = qs[wv];
    float* P = ps[wv];
    Q[lane] = bf2f(qkv[(long)tq * QKVLD + h * DH + lane]) * 0.125f;
    __syncthreads();
    float sc[8];
    float m = -1e30f;
#pragma unroll
    for (int jj = 0; jj < 8; jj++) {
        int j = lane + jj * 64;
        const u16* kr = qkv + (long)(b * S + j) * QKVLD + 1024 + hk * DH;
        float a = 0.f;
#pragma unroll
        for (int c = 0; c < 8; c++) {
            short8 kv8 = *(const short8*)(kr + c * 8);
#pragma unroll
            for (int u = 0; u < 8; u++) a += Q[c * 8 + u] * bf2f((u16)kv8[u]);
        }
        sc[jj] = a;
        m = fmaxf(m, a);
    }
#pragma unroll
    for (int o2 = 32; o2; o2 >>= 1) m = fmaxf(m, __shfl_xor(m, o2));
    float l = 0.f;
#pragma unroll
    for (int jj = 0; jj < 8; jj++) {
        float p = __expf(sc[jj] - m);
        P[lane + jj * 64] = p;
        l += p;
    }
#pragma unroll
    for (int o2 = 32; o2; o2 >>= 1) l += __shfl_xor(l, o2);
    __syncthreads();
    float inv = 1.f / l;
    float acc = 0.f;
    const u16* vb = qkv + (long)(b * S) * QKVLD + 1280 + hk * DH + lane;
#pragma unroll 4
    for (int j = 0; j < 512; j++) acc += P[j] * bf2f(vb[(long)j * QKVLD]);
    o[(long)tq * (HQ * DH) + h * DH + lane] = f2bf(acc * inv);
}

// ---------------- Router ----------------
__global__ __launch_bounds__(256) void router_k(const u16* __restrict__ t2,
                                                const float* __restrict__ rw,
                                                const float* __restrict__ rb,
                                                int* __restrict__ topi,
                                                float* __restrict__ probs) {
    int tid = threadIdx.x, lane = tid & 63, wv = tid >> 6;
    int tok = blockIdx.x * 4 + wv;
    float acc[NE] = {0.f, 0.f, 0.f, 0.f, 0.f, 0.f, 0.f, 0.f};
    for (int i = lane; i < H; i += 64) {
        float tv = bf2f(t2[(long)tok * H + i]);
        const float* r = rw + (long)i * NE;
        float4v ra = *(const float4v*)r;
        float4v rbv = *(const float4v*)(r + 4);
#pragma unroll
        for (int e = 0; e < 4; e++) acc[e] += tv * ra[e];
#pragma unroll
        for (int e = 0; e < 4; e++) acc[4 + e] += tv * rbv[e];
    }
#pragma unroll
    for (int e = 0; e < NE; e++)
#pragma unroll
        for (int o = 32; o; o >>= 1) acc[e] += __shfl_xor(acc[e], o);
    if (lane == 0) {
        float lg[NE];
#pragma unroll
        for (int e = 0; e < NE; e++) lg[e] = acc[e] + rb[e];
        int i0 = 0;
        float v0 = lg[0];
#pragma unroll
        for (int e = 1; e < NE; e++)
            if (lg[e] > v0) { v0 = lg[e]; i0 = e; }
        int i1 = -1;
        float v1 = -1e30f;
#pragma unroll
        for (int e = 0; e < NE; e++) {
            if (e == i0) continue;
            if (lg[e] > v1) { v1 = lg[e]; i1 = e; }
        }
        float ex = __expf(v1 - v0);
        float p0 = 1.f / (1.f + ex);
        topi[tok * 2] = i0;
        topi[tok * 2 + 1] = i1;
        probs[tok * 2] = p0;
        probs[tok * 2 + 1] = ex * p0;
    }
}

// ---------------- Build expert lists ----------------
__global__ void build_k(const int* __restrict__ topi, const float* __restrict__ probs,
                        int* __restrict__ gcnt, int* __restrict__ goff,
                        int* __restrict__ list, float* __restrict__ lscale) {
    __shared__ int cnt[NE], off[NE], fill[NE];
    int t = threadIdx.x;
    if (t < NE) cnt[t] = 0;
    __syncthreads();
    int e0 = topi[2 * t], e1 = topi[2 * t + 1];
    atomicAdd(&cnt[e0], 1);
    atomicAdd(&cnt[e1], 1);
    __syncthreads();
    if (t == 0) {
        int run = 0;
        for (int e = 0; e < NE; e++) {
            off[e] = run;
            fill[e] = run;
            run += cnt[e];
        }
    }
    __syncthreads();
    if (t < NE) {
        gcnt[t] = cnt[t];
        goff[t] = off[t];
    }
    int p0 = atomicAdd(&fill[e0], 1);
    list[p0] = t;
    lscale[p0] = probs[2 * t];
    int p1 = atomicAdd(&fill[e1], 1);
    list[p1] = t;
    lscale[p1] = probs[2 * t + 1];
}

__global__ void prep_bias_k(const float* __restrict__ qb, const float* __restrict__ kb,
                            const float* __restrict__ vb, float* __restrict__ qkvb) {
    int i = blockIdx.x * 256 + threadIdx.x;
    if (i < 1536) {
        float v = (i < 1024) ? qb[i] : ((i < 1280) ? kb[i - 1024] : vb[i - 1280]);
        qkvb[i] = v;
    }
}

__global__ void zero_k(float* __restrict__ p, int n) {
    int i = blockIdx.x * 256 + threadIdx.x;
    if (i < n) p[i] = 0.f;
}

__global__ void final_k(const float* __restrict__ x1, const float* __restrict__ moe,
                        float* __restrict__ out) {
    int i = blockIdx.x * 256 + threadIdx.x;
    out[i] = x1[i] + moe[i];
}

extern "C" void kernel_launch(void* const* d_in, const int* in_sizes, int n_in,
                              void* d_out, int out_size, void* d_ws, size_t ws_size,
                              hipStream_t stream) {
    const float* x = (const float*)d_in[0];
    const float* norm1_w = (const float*)d_in[1];
    const float* q_w = (const float*)d_in[2];
    const float* q_b = (const float*)d_in[3];
    const float* k_w = (const float*)d_in[4];
    const float* k_b = (const float*)d_in[5];
    const float* v_w = (const float*)d_in[6];
    const float* v_b = (const float*)d_in[7];
    const float* o_w = (const float*)d_in[8];
    const float* o_b = (const float*)d_in[9];
    const float* norm2_w = (const float*)d_in[10];
    const float* router_w = (const float*)d_in[11];
    const float* router_b = (const float*)d_in[12];
    const float* gate_w = (const float*)d_in[13];
    const float* gate_b = (const float*)d_in[14];
    const float* up_w = (const float*)d_in[15];
    const float* up_b = (const float*)d_in[16];
    const float* down_w = (const float*)d_in[17];
    const float* down_b = (const float*)d_in[18];

    char* w = (char*)d_ws;
    u16* qkvT = (u16*)w;          w += (long)1536 * 1024 * 2;
    u16* o_wt = (u16*)w;          w += (long)1024 * 1024 * 2;
    u16* gateT = (u16*)w;         w += (long)NE * NI * 1024 * 2;
    u16* upT = (u16*)w;           w += (long)NE * NI * 1024 * 2;
    u16* downT = (u16*)w;         w += (long)NE * 1024 * NI * 2;
    u16* h1 = (u16*)w;            w += (long)T * H * 2;
    u16* qkv = (u16*)w;           w += (long)T * 1536 * 2;
    float* qkvb = (float*)w;      w += 1536 * 4;
    u16* ao = (u16*)w;            w += (long)T * (HQ * DH) * 2;
    float* x1 = (float*)w;        w += (long)T * H * 4;
    u16* t2 = (u16*)w;            w += (long)T * H * 2;
    int* topi = (int*)w;          w += T * 2 * 4;
    float* probs = (float*)w;     w += T * 2 * 4;
    int* gcnt = (int*)w;          w += 64;
    int* goff = (int*)w;          w += 64;
    int* list = (int*)w;          w += 2048 * 4;
    float* lscale = (float*)w;    w += 2048 * 4;
    u16* act = (u16*)w;           w += (long)2048 * NI * 2;
    float* moe = (float*)w;       w += (long)T * H * 4;

    // ---- weight transposes (f32 -> bf16, [K][N] -> [N][K]) ----
    transpose_k<<<dim3(16, 16, 1), 256, 0, stream>>>(q_w, qkvT, 1024, 1024, 0, 0);
    transpose_k<<<dim3(4, 16, 1), 256, 0, stream>>>(k_w, qkvT + (long)1024 * 1024, 1024, 256, 0, 0);
    transpose_k<<<dim3(4, 16, 1), 256, 0, stream>>>(v_w, qkvT + (long)1280 * 1024, 1024, 256, 0, 0);
    transpose_k<<<dim3(16, 16, 1), 256, 0, stream>>>(o_w, o_wt, 1024, 1024, 0, 0);
    transpose_k<<<dim3(64, 16, NE), 256, 0, stream>>>(gate_w, gateT, 1024, NI,
                                                      (long)1024 * NI, (long)NI * 1024);
    transpose_k<<<dim3(64, 16, NE), 256, 0, stream>>>(up_w, upT, 1024, NI,
                                                      (long)1024 * NI, (long)NI * 1024);
    transpose_k<<<dim3(16, 64, NE), 256, 0, stream>>>(down_w, downT, NI, 1024,
                                                      (long)NI * 1024, (long)1024 * NI);
    prep_bias_k<<<6, 256, 0, stream>>>(q_b, k_b, v_b, qkvb);

    // 1. rmsnorm1
    rmsnorm_k<<<T, 256, 0, stream>>>(x, norm1_w, h1);
    // 2. fused QKV projection (N=1536)
    gemm128<1><<<dim3(12, 8, 1), 256, 0, stream>>>(h1, 1024, qkvT, nullptr, qkvb, nullptr,
                                                   nullptr, qkv, 1024, 1536, 1024,
                                                   nullptr, nullptr, nullptr, nullptr, nullptr, nullptr);
    // 3. attention
    attn_k<<<(BB * HQ * S) / 4, 256, 0, stream>>>(qkv, ao);
    // 4. O-proj + residual
    gemm128<2><<<dim3(8, 8, 1), 256, 0, stream>>>(ao, 1024, o_wt, nullptr, o_b, nullptr,
                                                  x, x1, 1024, 1024, 1024,
                                                  nullptr, nullptr, nullptr, nullptr, nullptr, nullptr);
    // 5. rmsnorm2
    rmsnorm_k<<<T, 256, 0, stream>>>(x1, norm2_w, t2);
    // 6. router
    router_k<<<T / 4, 256, 0, stream>>>(t2, router_w, router_b, topi, probs);
    // 7. build lists
    build_k<<<1, 1024, 0, stream>>>(topi, probs, gcnt, goff, list, lscale);
    // 8. zero moe
    zero_k<<<(T * H) / 256, 256, 0, stream>>>(moe, T * H);
    // 9. gate/up fused (gathered A, per-expert BT)
    gemm128<3><<<dim3(NI / 128, 8, NE), 256, 0, stream>>>(t2, 1024, gateT, upT,
                                                          gate_b, up_b, nullptr, nullptr,
                                                          0, NI, 1024,
                                                          gcnt, goff, list, lscale, act, nullptr);
    // 10. down + scatter
    gemm128<4><<<dim3(H / 128, 8, NE), 256, 0, stream>>>(act, NI, downT, nullptr,
                                                         down_b, nullptr, nullptr, nullptr,
                                                         0, H, NI,
                                                         gcnt, goff, list, lscale, nullptr, moe);
    // 11. final add
    final_k<<<(T * H) / 256, 256, 0, stream>>>(x1, moe, (float*)d_out);
}